// Round 10
// baseline (503.343 us; speedup 1.0000x reference)
//
#include <hip/hip_runtime.h>
#include <hip/hip_bf16.h>

#define CAP 64          // max real in-neighbors kept per dst (self-loop is implicit)
#define EPSBN 1e-5f
#define NEG_SLOPE 0.2f
#define NPARAM 24       // float param tensors: d_in[3..26]
#define POOL_SPLIT 4    // blocks per graph in pooling

typedef __attribute__((ext_vector_type(8))) short short8;
typedef __attribute__((ext_vector_type(4))) float f32x4;

static __device__ __forceinline__ float b2f(__hip_bfloat16 v) { return __bfloat162float(v); }
static __device__ __forceinline__ float u2f(unsigned short u) {  // bf16 bits -> float
    return __uint_as_float(((unsigned int)u) << 16);
}
static __device__ __forceinline__ unsigned short f2b_rne(float f) {  // float -> bf16, RNE
    unsigned int u = __float_as_uint(f);
    u += 0x7FFF + ((u >> 16) & 1);
    return (unsigned short)(u >> 16);
}
static __device__ __forceinline__ bool is_f32(const int* flagcnt) { return *flagcnt > 32; }

// ---------------- dtype probe ----------------
__global__ void k_detect(const unsigned short* __restrict__ raw, int* flagcnt) {
    int t = threadIdx.x;  // 256 threads, 1 block
    int c = 0;
    for (int i = t; i < 4096; i += 256) {
        int e = (raw[i] >> 7) & 0xFF;
        if (e >= 200) c++;
    }
    atomicAdd(flagcnt, c);
}

// ---------------- merged prep: x->bf16, params->fp32, W0/1/2 -> transposed bf16 ------
struct CvtTab {
    const void* src[NPARAM];
    float* dst[NPARAM];
    int off[NPARAM + 1];
};

__global__ void k_prep(const void* __restrict__ x_in, unsigned short* __restrict__ xb16,
                       CvtTab tab,
                       unsigned short* __restrict__ Wt0, unsigned short* __restrict__ Wt1,
                       unsigned short* __restrict__ Wt2,
                       const int* flagcnt, int NX, int ptot) {
    bool f32 = is_f32(flagcnt);
    const void* W0r = tab.src[0];
    const void* W1r = tab.src[6];
    const void* W2r = tab.src[12];
    int b0 = NX, b1 = b0 + ptot, b2 = b1 + 256 * 128, b3 = b2 + 256 * 256, b4 = b3 + 128 * 256;
    for (int i = blockIdx.x * blockDim.x + threadIdx.x; i < b4; i += gridDim.x * blockDim.x) {
        if (i < b0) {
            xb16[i] = f32 ? f2b_rne(((const float*)x_in)[i]) : ((const unsigned short*)x_in)[i];
        } else if (i < b1) {
            int ii = i - b0;
            int j = 0;
            while (tab.off[j + 1] <= ii) j++;
            int k = ii - tab.off[j];
            tab.dst[j][k] = f32 ? ((const float*)tab.src[j])[k]
                                : b2f(((const __hip_bfloat16*)tab.src[j])[k]);
        } else if (i < b2) {         // Wt0 [F=256][K=128] <- W0 [128,256]
            int ii = i - b1;
            int f = ii >> 7, k = ii & 127;
            long src = (long)k * 256 + f;
            Wt0[ii] = f32 ? f2b_rne(((const float*)W0r)[src]) : ((const unsigned short*)W0r)[src];
        } else if (i < b3) {         // Wt1 [256][256] <- W1 [256,256]
            int ii = i - b2;
            int f = ii >> 8, k = ii & 255;
            long src = (long)k * 256 + f;
            Wt1[ii] = f32 ? f2b_rne(((const float*)W1r)[src]) : ((const unsigned short*)W1r)[src];
        } else {                     // Wt2 [F=128][K=256] <- W2 [256,128]
            int ii = i - b3;
            int f = ii >> 8, k = ii & 255;
            long src = (long)k * 128 + f;
            Wt2[ii] = f32 ? f2b_rne(((const float*)W2r)[src]) : ((const unsigned short*)W2r)[src];
        }
    }
}

// ---------------- graph build (cnt pre-zeroed by memset; self-loop implicit) ---------
__global__ void k_fill_graph(const int* __restrict__ ei, int* cnt, int* adj, int E) {
    int e = blockIdx.x * blockDim.x + threadIdx.x;
    if (e < E) {
        int s = ei[e];
        int d = ei[E + e];
        int slot = atomicAdd(&cnt[d], 1);
        if (slot < CAP) adj[d * CAP + slot] = s;
    }
}

// ---------------- bf16 MFMA GEMM, optional fused BN+ReLU on the A operand -----------
// C[M,F] = bn(A)[M,K] @ Bt[F,K]^T.  bn(x) = relu(x*scale[k]+shift[k]) if scale!=null.
__global__ __launch_bounds__(256) void k_gemm_mfma(const unsigned short* __restrict__ A,
                                                   const unsigned short* __restrict__ Bt,
                                                   unsigned short* __restrict__ C,
                                                   const float* __restrict__ scale,
                                                   const float* __restrict__ shift,
                                                   int M, int K, int F) {
    __shared__ __align__(16) unsigned short As[64 * 40];
    __shared__ __align__(16) unsigned short Bs[64 * 40];
    int t = threadIdx.x;
    int lane = t & 63, wave = t >> 6;
    int wm = wave & 1, wf = wave >> 1;
    int m0 = blockIdx.x * 64, f0 = blockIdx.y * 64;
    int r = lane & 15, q = lane >> 4;
    int srow = t >> 2, schunk = t & 3;
    f32x4 acc[2][2] = {};
    for (int k0 = 0; k0 < K; k0 += 32) {
        uint4 av = {0, 0, 0, 0};
        int gr = m0 + srow;
        if (gr < M) {
            av = *(const uint4*)(A + (long)gr * K + k0 + schunk * 8);
            if (scale) {
                int fb = k0 + schunk * 8;
                float4 s0 = *(const float4*)(scale + fb);
                float4 s1 = *(const float4*)(scale + fb + 4);
                float4 h0 = *(const float4*)(shift + fb);
                float4 h1 = *(const float4*)(shift + fb + 4);
                unsigned short* ev = (unsigned short*)&av;
                ev[0] = f2b_rne(fmaxf(u2f(ev[0]) * s0.x + h0.x, 0.f));
                ev[1] = f2b_rne(fmaxf(u2f(ev[1]) * s0.y + h0.y, 0.f));
                ev[2] = f2b_rne(fmaxf(u2f(ev[2]) * s0.z + h0.z, 0.f));
                ev[3] = f2b_rne(fmaxf(u2f(ev[3]) * s0.w + h0.w, 0.f));
                ev[4] = f2b_rne(fmaxf(u2f(ev[4]) * s1.x + h1.x, 0.f));
                ev[5] = f2b_rne(fmaxf(u2f(ev[5]) * s1.y + h1.y, 0.f));
                ev[6] = f2b_rne(fmaxf(u2f(ev[6]) * s1.z + h1.z, 0.f));
                ev[7] = f2b_rne(fmaxf(u2f(ev[7]) * s1.w + h1.w, 0.f));
            }
        }
        *(uint4*)&As[srow * 40 + schunk * 8] = av;
        uint4 bv = *(const uint4*)(Bt + (long)(f0 + srow) * K + k0 + schunk * 8);
        *(uint4*)&Bs[srow * 40 + schunk * 8] = bv;
        __syncthreads();
        short8 a0 = *(short8*)&As[(wm * 32 + r) * 40 + q * 8];
        short8 a1 = *(short8*)&As[(wm * 32 + 16 + r) * 40 + q * 8];
        short8 b0 = *(short8*)&Bs[(wf * 32 + r) * 40 + q * 8];
        short8 b1 = *(short8*)&Bs[(wf * 32 + 16 + r) * 40 + q * 8];
        acc[0][0] = __builtin_amdgcn_mfma_f32_16x16x32_bf16(a0, b0, acc[0][0], 0, 0, 0);
        acc[0][1] = __builtin_amdgcn_mfma_f32_16x16x32_bf16(a0, b1, acc[0][1], 0, 0, 0);
        acc[1][0] = __builtin_amdgcn_mfma_f32_16x16x32_bf16(a1, b0, acc[1][0], 0, 0, 0);
        acc[1][1] = __builtin_amdgcn_mfma_f32_16x16x32_bf16(a1, b1, acc[1][1], 0, 0, 0);
        __syncthreads();
    }
    #pragma unroll
    for (int mt = 0; mt < 2; mt++) {
        #pragma unroll
        for (int reg = 0; reg < 4; reg++) {
            int row = m0 + wm * 32 + mt * 16 + q * 4 + reg;
            if (row < M) {
                C[(long)row * F + f0 + wf * 32 + r]      = f2b_rne(acc[mt][0][reg]);
                C[(long)row * F + f0 + wf * 32 + 16 + r] = f2b_rne(acc[mt][1][reg]);
            }
        }
    }
}

// ---------------- fused attention: coefficients + softmax + aggregation --------------
template <int F, int H>
__global__ __launch_bounds__(256) void k_agg(const unsigned short* __restrict__ h,
                      const int* __restrict__ cnt, const int* __restrict__ adj,
                      const float* __restrict__ a_s, const float* __restrict__ a_d,
                      const float* __restrict__ bias,
                      unsigned short* __restrict__ out, int n) {
    const int VPL = F / 64;
    const int LPH = 64 / H;   // lanes per head
    int lane = threadIdx.x & 63;
    int dst = (blockIdx.x * blockDim.x + threadIdx.x) >> 6;
    if (dst >= n) return;
    float asv[VPL], adv[VPL];
    #pragma unroll
    for (int j = 0; j < VPL; j++) {
        asv[j] = a_s[lane * VPL + j];
        adv[j] = a_d[lane * VPL + j];
    }
    float hs[VPL];
    {
        const unsigned short* hp = h + (long)dst * F + lane * VPL;
        if (VPL == 4) {
            uint2 hv = *(const uint2*)hp;
            hs[0] = __uint_as_float(hv.x << 16); hs[1] = __uint_as_float(hv.x & 0xffff0000u);
            hs[2] = __uint_as_float(hv.y << 16); hs[3] = __uint_as_float(hv.y & 0xffff0000u);
        } else {
            unsigned int hv = *(const unsigned int*)hp;
            hs[0] = __uint_as_float(hv << 16); hs[1] = __uint_as_float(hv & 0xffff0000u);
        }
    }
    float ps = 0.f, pd = 0.f;
    #pragma unroll
    for (int j = 0; j < VPL; j++) { ps += hs[j] * asv[j]; pd += hs[j] * adv[j]; }
    #pragma unroll
    for (int m = 1; m < LPH; m <<= 1) {
        ps += __shfl_xor(ps, m, 64);
        pd += __shfl_xor(pd, m, 64);
    }
    float ed_dst = pd;
    float e = ps + ed_dst;
    e = fmaxf(e, NEG_SLOPE * e);
    float w = __expf(e);
    float z = w;
    float acc[VPL];
    #pragma unroll
    for (int j = 0; j < VPL; j++) acc[j] = w * hs[j];

    int deg = min(cnt[dst], CAP);
    const int* ap = adj + (long)dst * CAP;
    int sl = 0;
    if (deg > 0) sl = ap[lane < deg ? lane : deg - 1];
    for (int base = 0; base < deg; base += 8) {
        float hv[8][VPL];
        #pragma unroll
        for (int c = 0; c < 8; c++) {
            int idx = base + c;
            int ii = idx < deg ? idx : deg - 1;   // wave-uniform pad
            int s = __builtin_amdgcn_readlane(sl, ii);
            const unsigned short* hp = h + (long)s * F + lane * VPL;
            if (VPL == 4) {
                uint2 hb = *(const uint2*)hp;
                hv[c][0] = __uint_as_float(hb.x << 16);
                hv[c][1] = __uint_as_float(hb.x & 0xffff0000u);
                hv[c][2] = __uint_as_float(hb.y << 16);
                hv[c][3] = __uint_as_float(hb.y & 0xffff0000u);
            } else {
                unsigned int hb = *(const unsigned int*)hp;
                hv[c][0] = __uint_as_float(hb << 16);
                hv[c][1] = __uint_as_float(hb & 0xffff0000u);
            }
        }
        #pragma unroll
        for (int c = 0; c < 8; c++) {
            float p = 0.f;
            #pragma unroll
            for (int j = 0; j < VPL; j++) p += hv[c][j] * asv[j];
            #pragma unroll
            for (int m = 1; m < LPH; m <<= 1) p += __shfl_xor(p, m, 64);
            float ee = p + ed_dst;
            ee = fmaxf(ee, NEG_SLOPE * ee);
            float ww = __expf(ee);
            if (base + c >= deg) ww = 0.f;        // pad contributes nothing
            z += ww;
            #pragma unroll
            for (int j = 0; j < VPL; j++) acc[j] += ww * hv[c][j];
        }
    }
    float invz = 1.f / z;
    unsigned short pk[VPL];
    #pragma unroll
    for (int j = 0; j < VPL; j++)
        pk[j] = f2b_rne(acc[j] * invz + bias[lane * VPL + j]);
    if (VPL == 4) *(ushort4*)(out + (long)dst * F + lane * 4) = *(ushort4*)pk;
    else          *(ushort2*)(out + (long)dst * F + lane * 2) = *(ushort2*)pk;
}

// ---------------- batchnorm stats (vectorized) + last-block fold --------------------
// Thread owns 8 fixed features, loads uint4 (16B/lane, coalesced: 256 thr = RPI rows/iter).
// LDS reduce across row-phases (stride-9 padding, <=2-way banks), F atomics per block.
template <int F>
__global__ __launch_bounds__(256) void k_bnstats(const unsigned short* __restrict__ x,
                          float* __restrict__ bnsum, float* __restrict__ bnsq,
                          const float* __restrict__ gamma, const float* __restrict__ beta,
                          float* __restrict__ scale, float* __restrict__ shift,
                          int* __restrict__ done, float invN, int n) {
    const int TPR = F / 8;        // threads per row
    const int RPI = 256 / TPR;    // rows per iteration
    __shared__ float sm[256 * 9];
    __shared__ int lastFlag;
    int t = threadIdx.x;
    int fr = t % TPR;
    int rp = t / TPR;
    int f0 = fr * 8;
    float s[8] = {}, q[8] = {};
    for (int r = blockIdx.x * RPI + rp; r < n; r += gridDim.x * RPI) {
        uint4 v = *(const uint4*)(x + (long)r * F + f0);
        const unsigned short* ev = (const unsigned short*)&v;
        #pragma unroll
        for (int j = 0; j < 8; j++) {
            float f = u2f(ev[j]);
            s[j] += f; q[j] += f * f;
        }
    }
    #pragma unroll
    for (int j = 0; j < 8; j++) sm[t * 9 + j] = s[j];
    __syncthreads();
    if (rp == 0) {
        float a[8];
        #pragma unroll
        for (int j = 0; j < 8; j++) a[j] = sm[fr * 9 + j];
        for (int p = 1; p < RPI; p++)
            #pragma unroll
            for (int j = 0; j < 8; j++) a[j] += sm[(p * TPR + fr) * 9 + j];
        #pragma unroll
        for (int j = 0; j < 8; j++) atomicAdd(&bnsum[f0 + j], a[j]);
    }
    __syncthreads();
    #pragma unroll
    for (int j = 0; j < 8; j++) sm[t * 9 + j] = q[j];
    __syncthreads();
    if (rp == 0) {
        float a[8];
        #pragma unroll
        for (int j = 0; j < 8; j++) a[j] = sm[fr * 9 + j];
        for (int p = 1; p < RPI; p++)
            #pragma unroll
            for (int j = 0; j < 8; j++) a[j] += sm[(p * TPR + fr) * 9 + j];
        #pragma unroll
        for (int j = 0; j < 8; j++) atomicAdd(&bnsq[f0 + j], a[j]);
    }
    __threadfence();
    if (t == 0) {
        int old = atomicAdd(done, 1);
        lastFlag = (old == (int)gridDim.x - 1);
    }
    __syncthreads();
    if (lastFlag && t < F) {
        __threadfence();  // acquire
        float mu = bnsum[t] * invN;
        float var = bnsq[t] * invN - mu * mu;
        float sc = gamma[t] * rsqrtf(var + EPSBN);
        scale[t] = sc;
        shift[t] = beta[t] - mu * sc;
    }
}

// ---------------- graph mean-pool (vectorized) with fused layer-2 BN+ReLU -----------
static __device__ __forceinline__ int lower_bound_i(const int* __restrict__ a, int n, int v) {
    int lo = 0, hi = n;
    while (lo < hi) { int mid = (lo + hi) >> 1; if (a[mid] < v) lo = mid + 1; else hi = mid; }
    return lo;
}

__global__ __launch_bounds__(256) void k_pool2(const unsigned short* __restrict__ x,
                                               const int* __restrict__ batch,
                                               const float* __restrict__ scale,
                                               const float* __restrict__ shift,
                                               float* __restrict__ featsum,
                                               int* __restrict__ gcnt, int n) {
    const int TPR = 32;           // threads per row (128 feats / 4 per thread)
    const int RPI = 8;            // rows per iteration
    __shared__ float sm[256 * 5];
    int g = blockIdx.x / POOL_SPLIT;
    int part = blockIdx.x % POOL_SPLIT;
    int t = threadIdx.x;
    int fr = t % TPR;
    int rp = t / TPR;
    int f0 = fr * 4;
    int lo = lower_bound_i(batch, n, g);
    int hi = lower_bound_i(batch, n, g + 1);
    float4 sc = *(const float4*)(scale + f0);
    float4 sh = *(const float4*)(shift + f0);
    float a0 = 0.f, a1 = 0.f, a2 = 0.f, a3 = 0.f;
    for (int r = lo + part * RPI + rp; r < hi; r += POOL_SPLIT * RPI) {
        uint2 v = *(const uint2*)(x + (long)r * 128 + f0);
        a0 += fmaxf(u2f((unsigned short)(v.x & 0xffff)) * sc.x + sh.x, 0.f);
        a1 += fmaxf(u2f((unsigned short)(v.x >> 16))    * sc.y + sh.y, 0.f);
        a2 += fmaxf(u2f((unsigned short)(v.y & 0xffff)) * sc.z + sh.z, 0.f);
        a3 += fmaxf(u2f((unsigned short)(v.y >> 16))    * sc.w + sh.w, 0.f);
    }
    sm[t * 5 + 0] = a0; sm[t * 5 + 1] = a1; sm[t * 5 + 2] = a2; sm[t * 5 + 3] = a3;
    __syncthreads();
    if (rp == 0) {
        float b[4];
        #pragma unroll
        for (int j = 0; j < 4; j++) b[j] = sm[fr * 5 + j];
        for (int p = 1; p < RPI; p++)
            #pragma unroll
            for (int j = 0; j < 4; j++) b[j] += sm[(p * TPR + fr) * 5 + j];
        #pragma unroll
        for (int j = 0; j < 4; j++) atomicAdd(&featsum[g * 128 + f0 + j], b[j]);
    }
    if (t == 0 && part == 0) gcnt[g] = hi - lo;
}

// ---------------- heads ----------------
__global__ void k_head(const float* __restrict__ featsum, const int* __restrict__ gcnt,
                       const float* __restrict__ clfW, const float* __restrict__ clfb,
                       const float* __restrict__ dW1, const float* __restrict__ db1,
                       const float* __restrict__ dW2, const float* __restrict__ db2,
                       void* __restrict__ out, const int* flagcnt, int G) {
    __shared__ float feat[128];
    __shared__ float dh[64];
    bool f32o = is_f32(flagcnt);
    float* of = (float*)out;
    __hip_bfloat16* ob = (__hip_bfloat16*)out;
    int g = blockIdx.x, t = threadIdx.x;  // 128 threads
    float c = fmaxf((float)gcnt[g], 1.f);
    float fv = featsum[g * 128 + t] / c;
    feat[t] = fv;
    int fidx = G * 10 + G * 2 + g * 128 + t;
    if (f32o) of[fidx] = fv; else ob[fidx] = __float2bfloat16(fv);
    __syncthreads();
    if (t < 10) {
        float a = clfb[t];
        for (int k = 0; k < 128; k++) a += feat[k] * clfW[k * 10 + t];
        int idx = g * 10 + t;
        if (f32o) of[idx] = a; else ob[idx] = __float2bfloat16(a);
    }
    if (t < 64) {
        float a = db1[t];
        for (int k = 0; k < 128; k++) a += feat[k] * dW1[k * 64 + t];
        dh[t] = a > 0.f ? a : 0.f;
    }
    __syncthreads();
    if (t < 2) {
        float a = db2[t];
        for (int k = 0; k < 64; k++) a += dh[k] * dW2[k * 2 + t];
        int idx = G * 10 + g * 2 + t;
        if (f32o) of[idx] = a; else ob[idx] = __float2bfloat16(a);
    }
}

// ---------------- launch ----------------
extern "C" void kernel_launch(void* const* d_in, const int* in_sizes, int n_in,
                              void* d_out, int out_size, void* d_ws, size_t ws_size,
                              hipStream_t stream) {
    const void* x_in = d_in[0];
    const int* ei    = (const int*)d_in[1];
    const int* batch = (const int*)d_in[2];
    const int N = in_sizes[2];
    const int E = in_sizes[1] / 2;
    const int G = 64;

    char* ws = (char*)d_ws;
    size_t off = 0;
    auto alloc = [&](size_t bytes) {
        void* p = ws + off;
        off += (bytes + 255) & ~(size_t)255;
        return p;
    };

    // ---- contiguous zero region (single memset) ----
    size_t zstart = off;
    int*   flagcnt   = (int*)alloc(256);         // [0]=flag, [1..3]=bn done counters
    int*   done0 = flagcnt + 1, *done1 = flagcnt + 2, *done2 = flagcnt + 3;
    float* bnsum_all = (float*)alloc(3 * 512 * 4);            // [layer][sum|sq]
    float* featsum   = (float*)alloc((size_t)G * 128 * 4 + (size_t)G * 4);
    int*   gcnt      = (int*)(featsum + G * 128);
    int*   cnt       = (int*)alloc((size_t)N * 4);
    size_t zbytes = off - zstart;

    int*   adj     = (int*)alloc((size_t)N * CAP * 4);
    unsigned short* xbuf16 = (unsigned short*)alloc((size_t)N * 256 * 2);  // agg out bf16
    unsigned short* hbuf   = (unsigned short*)alloc((size_t)N * 256 * 2);  // gemm out bf16
    unsigned short* xb16   = (unsigned short*)alloc((size_t)N * 256 * 2);  // x bf16 (L0 A)
    unsigned short* Wt0    = (unsigned short*)alloc((size_t)256 * 128 * 2);
    unsigned short* Wt1    = (unsigned short*)alloc((size_t)256 * 256 * 2);
    unsigned short* Wt2    = (unsigned short*)alloc((size_t)128 * 256 * 2);
    float* bnscale = (float*)alloc(3 * 512 * 4);              // [layer][scale|shift]

    float* bnsum0 = bnsum_all,        *bnsq0 = bnsum_all + 256;
    float* bnsum1 = bnsum_all + 512,  *bnsq1 = bnsum_all + 768;
    float* bnsum2 = bnsum_all + 1024, *bnsq2 = bnsum_all + 1280;
    float* sc0 = bnscale,        *sh0 = bnscale + 256;
    float* sc1 = bnscale + 512,  *sh1 = bnscale + 768;
    float* sc2 = bnscale + 1024, *sh2 = bnscale + 1280;

    // fp32 copies of the 24 float param tensors (d_in[3..26])
    CvtTab tab;
    float* pp[NPARAM];
    int ptot = 0;
    for (int j = 0; j < NPARAM; j++) {
        int cnt_j = in_sizes[3 + j];
        pp[j] = (float*)alloc((size_t)cnt_j * 4);
        tab.src[j] = d_in[3 + j];
        tab.dst[j] = pp[j];
        tab.off[j] = ptot;
        ptot += cnt_j;
    }
    tab.off[NPARAM] = ptot;
    float *asf0 = pp[1], *adf0 = pp[2], *bf0 = pp[3], *gf0 = pp[4], *bef0 = pp[5];
    float *asf1 = pp[7], *adf1 = pp[8], *bf1 = pp[9], *gf1 = pp[10], *bef1 = pp[11];
    float *asf2 = pp[13], *adf2 = pp[14], *bf2 = pp[15], *gf2 = pp[16], *bef2 = pp[17];
    float *clfWf = pp[18], *clfbf = pp[19], *dW1f = pp[20], *db1f = pp[21], *dW2f = pp[22], *db2f = pp[23];

    const int TPB = 256;
    int wgrid = (N + 3) / 4;
    int mblocks = (N + 63) / 64;
    float invN = 1.f / (float)N;

    hipMemsetAsync(ws + zstart, 0, zbytes, stream);
    k_detect<<<1, 256, 0, stream>>>((const unsigned short*)x_in, flagcnt);
    k_prep<<<2048, TPB, 0, stream>>>(x_in, xb16, tab, Wt0, Wt1, Wt2, flagcnt, N * 128, ptot);
    k_fill_graph<<<(E + TPB - 1) / TPB, TPB, 0, stream>>>(ei, cnt, adj, E);

    // ---- layer 0: K=128 -> F=256, H=4 (no input BN) ----
    k_gemm_mfma<<<dim3(mblocks, 4), 256, 0, stream>>>(xb16, Wt0, hbuf, nullptr, nullptr, N, 128, 256);
    k_agg<256, 4><<<wgrid, 256, 0, stream>>>(hbuf, cnt, adj, asf0, adf0, bf0, xbuf16, N);
    k_bnstats<256><<<256, 256, 0, stream>>>(xbuf16, bnsum0, bnsq0, gf0, bef0, sc0, sh0, done0, invN, N);

    // ---- layer 1: K=256 -> F=256, H=4 (BN0 fused into A-staging) ----
    k_gemm_mfma<<<dim3(mblocks, 4), 256, 0, stream>>>(xbuf16, Wt1, hbuf, sc0, sh0, N, 256, 256);
    k_agg<256, 4><<<wgrid, 256, 0, stream>>>(hbuf, cnt, adj, asf1, adf1, bf1, xbuf16, N);
    k_bnstats<256><<<256, 256, 0, stream>>>(xbuf16, bnsum1, bnsq1, gf1, bef1, sc1, sh1, done1, invN, N);

    // ---- layer 2: K=256 -> F=128, H=1 (BN1 fused into A-staging) ----
    k_gemm_mfma<<<dim3(mblocks, 2), 256, 0, stream>>>(xbuf16, Wt2, hbuf, sc1, sh1, N, 256, 128);
    k_agg<128, 1><<<wgrid, 256, 0, stream>>>(hbuf, cnt, adj, asf2, adf2, bf2, xbuf16, N);
    k_bnstats<128><<<256, 256, 0, stream>>>(xbuf16, bnsum2, bnsq2, gf2, bef2, sc2, sh2, done2, invN, N);

    // ---- pooling (BN2 fused) + heads ----
    k_pool2<<<G * POOL_SPLIT, 256, 0, stream>>>(xbuf16, batch, sc2, sh2, featsum, gcnt, N);
    k_head<<<G, 128, 0, stream>>>(featsum, gcnt, clfWf, clfbf, dW1f, db1f, dW2f, db2f,
                                  d_out, flagcnt, G);
}

// Round 11
// 503.237 us; speedup vs baseline: 1.0002x; 1.0002x over previous
//
#include <hip/hip_runtime.h>
#include <hip/hip_bf16.h>

#define CAP 64          // max real in-neighbors kept per dst (self-loop is implicit)
#define EPSBN 1e-5f
#define NEG_SLOPE 0.2f
#define NPARAM 24       // float param tensors: d_in[3..26]
#define POOL_SPLIT 4    // blocks per graph in pooling
#define BNB 256         // blocks for bn partial pass

typedef __attribute__((ext_vector_type(8))) short short8;
typedef __attribute__((ext_vector_type(4))) float f32x4;

static __device__ __forceinline__ float b2f(__hip_bfloat16 v) { return __bfloat162float(v); }
static __device__ __forceinline__ float u2f(unsigned short u) {  // bf16 bits -> float
    return __uint_as_float(((unsigned int)u) << 16);
}
static __device__ __forceinline__ unsigned short f2b_rne(float f) {  // float -> bf16, RNE
    unsigned int u = __float_as_uint(f);
    u += 0x7FFF + ((u >> 16) & 1);
    return (unsigned short)(u >> 16);
}
static __device__ __forceinline__ bool is_f32(const int* flagcnt) { return *flagcnt > 32; }

// ---------------- dtype probe ----------------
__global__ void k_detect(const unsigned short* __restrict__ raw, int* flagcnt) {
    int t = threadIdx.x;  // 256 threads, 1 block
    int c = 0;
    for (int i = t; i < 4096; i += 256) {
        int e = (raw[i] >> 7) & 0xFF;
        if (e >= 200) c++;
    }
    atomicAdd(flagcnt, c);
}

// ---------------- merged prep: x->bf16, params->fp32, W0/1/2 -> transposed bf16 ------
struct CvtTab {
    const void* src[NPARAM];
    float* dst[NPARAM];
    int off[NPARAM + 1];
};

__global__ void k_prep(const void* __restrict__ x_in, unsigned short* __restrict__ xb16,
                       CvtTab tab,
                       unsigned short* __restrict__ Wt0, unsigned short* __restrict__ Wt1,
                       unsigned short* __restrict__ Wt2,
                       const int* flagcnt, int NX, int ptot) {
    bool f32 = is_f32(flagcnt);
    const void* W0r = tab.src[0];
    const void* W1r = tab.src[6];
    const void* W2r = tab.src[12];
    int b0 = NX, b1 = b0 + ptot, b2 = b1 + 256 * 128, b3 = b2 + 256 * 256, b4 = b3 + 128 * 256;
    for (int i = blockIdx.x * blockDim.x + threadIdx.x; i < b4; i += gridDim.x * blockDim.x) {
        if (i < b0) {
            xb16[i] = f32 ? f2b_rne(((const float*)x_in)[i]) : ((const unsigned short*)x_in)[i];
        } else if (i < b1) {
            int ii = i - b0;
            int j = 0;
            while (tab.off[j + 1] <= ii) j++;
            int k = ii - tab.off[j];
            tab.dst[j][k] = f32 ? ((const float*)tab.src[j])[k]
                                : b2f(((const __hip_bfloat16*)tab.src[j])[k]);
        } else if (i < b2) {         // Wt0 [F=256][K=128] <- W0 [128,256]
            int ii = i - b1;
            int f = ii >> 7, k = ii & 127;
            long src = (long)k * 256 + f;
            Wt0[ii] = f32 ? f2b_rne(((const float*)W0r)[src]) : ((const unsigned short*)W0r)[src];
        } else if (i < b3) {         // Wt1 [256][256] <- W1 [256,256]
            int ii = i - b2;
            int f = ii >> 8, k = ii & 255;
            long src = (long)k * 256 + f;
            Wt1[ii] = f32 ? f2b_rne(((const float*)W1r)[src]) : ((const unsigned short*)W1r)[src];
        } else {                     // Wt2 [F=128][K=256] <- W2 [256,128]
            int ii = i - b3;
            int f = ii >> 8, k = ii & 255;
            long src = (long)k * 128 + f;
            Wt2[ii] = f32 ? f2b_rne(((const float*)W2r)[src]) : ((const unsigned short*)W2r)[src];
        }
    }
}

// ---------------- graph build (cnt pre-zeroed by memset; self-loop implicit) ---------
__global__ void k_fill_graph(const int* __restrict__ ei, int* cnt, int* adj, int E) {
    int e = blockIdx.x * blockDim.x + threadIdx.x;
    if (e < E) {
        int s = ei[e];
        int d = ei[E + e];
        int slot = atomicAdd(&cnt[d], 1);
        if (slot < CAP) adj[d * CAP + slot] = s;
    }
}

// ---------------- bf16 MFMA GEMM, optional fused BN+ReLU on the A operand -----------
// C[M,F] = bn(A)[M,K] @ Bt[F,K]^T.  bn(x) = relu(x*scale[k]+shift[k]) if scale!=null.
__global__ __launch_bounds__(256) void k_gemm_mfma(const unsigned short* __restrict__ A,
                                                   const unsigned short* __restrict__ Bt,
                                                   unsigned short* __restrict__ C,
                                                   const float* __restrict__ scale,
                                                   const float* __restrict__ shift,
                                                   int M, int K, int F) {
    __shared__ __align__(16) unsigned short As[64 * 40];
    __shared__ __align__(16) unsigned short Bs[64 * 40];
    int t = threadIdx.x;
    int lane = t & 63, wave = t >> 6;
    int wm = wave & 1, wf = wave >> 1;
    int m0 = blockIdx.x * 64, f0 = blockIdx.y * 64;
    int r = lane & 15, q = lane >> 4;
    int srow = t >> 2, schunk = t & 3;
    f32x4 acc[2][2] = {};
    for (int k0 = 0; k0 < K; k0 += 32) {
        uint4 av = {0, 0, 0, 0};
        int gr = m0 + srow;
        if (gr < M) {
            av = *(const uint4*)(A + (long)gr * K + k0 + schunk * 8);
            if (scale) {
                int fb = k0 + schunk * 8;
                float4 s0 = *(const float4*)(scale + fb);
                float4 s1 = *(const float4*)(scale + fb + 4);
                float4 h0 = *(const float4*)(shift + fb);
                float4 h1 = *(const float4*)(shift + fb + 4);
                unsigned short* ev = (unsigned short*)&av;
                ev[0] = f2b_rne(fmaxf(u2f(ev[0]) * s0.x + h0.x, 0.f));
                ev[1] = f2b_rne(fmaxf(u2f(ev[1]) * s0.y + h0.y, 0.f));
                ev[2] = f2b_rne(fmaxf(u2f(ev[2]) * s0.z + h0.z, 0.f));
                ev[3] = f2b_rne(fmaxf(u2f(ev[3]) * s0.w + h0.w, 0.f));
                ev[4] = f2b_rne(fmaxf(u2f(ev[4]) * s1.x + h1.x, 0.f));
                ev[5] = f2b_rne(fmaxf(u2f(ev[5]) * s1.y + h1.y, 0.f));
                ev[6] = f2b_rne(fmaxf(u2f(ev[6]) * s1.z + h1.z, 0.f));
                ev[7] = f2b_rne(fmaxf(u2f(ev[7]) * s1.w + h1.w, 0.f));
            }
        }
        *(uint4*)&As[srow * 40 + schunk * 8] = av;
        uint4 bv = *(const uint4*)(Bt + (long)(f0 + srow) * K + k0 + schunk * 8);
        *(uint4*)&Bs[srow * 40 + schunk * 8] = bv;
        __syncthreads();
        short8 a0 = *(short8*)&As[(wm * 32 + r) * 40 + q * 8];
        short8 a1 = *(short8*)&As[(wm * 32 + 16 + r) * 40 + q * 8];
        short8 b0 = *(short8*)&Bs[(wf * 32 + r) * 40 + q * 8];
        short8 b1 = *(short8*)&Bs[(wf * 32 + 16 + r) * 40 + q * 8];
        acc[0][0] = __builtin_amdgcn_mfma_f32_16x16x32_bf16(a0, b0, acc[0][0], 0, 0, 0);
        acc[0][1] = __builtin_amdgcn_mfma_f32_16x16x32_bf16(a0, b1, acc[0][1], 0, 0, 0);
        acc[1][0] = __builtin_amdgcn_mfma_f32_16x16x32_bf16(a1, b0, acc[1][0], 0, 0, 0);
        acc[1][1] = __builtin_amdgcn_mfma_f32_16x16x32_bf16(a1, b1, acc[1][1], 0, 0, 0);
        __syncthreads();
    }
    #pragma unroll
    for (int mt = 0; mt < 2; mt++) {
        #pragma unroll
        for (int reg = 0; reg < 4; reg++) {
            int row = m0 + wm * 32 + mt * 16 + q * 4 + reg;
            if (row < M) {
                C[(long)row * F + f0 + wf * 32 + r]      = f2b_rne(acc[mt][0][reg]);
                C[(long)row * F + f0 + wf * 32 + 16 + r] = f2b_rne(acc[mt][1][reg]);
            }
        }
    }
}

// ---------------- fused attention: coefficients + softmax + aggregation --------------
template <int F, int H>
__global__ __launch_bounds__(256) void k_agg(const unsigned short* __restrict__ h,
                      const int* __restrict__ cnt, const int* __restrict__ adj,
                      const float* __restrict__ a_s, const float* __restrict__ a_d,
                      const float* __restrict__ bias,
                      unsigned short* __restrict__ out, int n) {
    const int VPL = F / 64;
    const int LPH = 64 / H;   // lanes per head
    int lane = threadIdx.x & 63;
    int dst = (blockIdx.x * blockDim.x + threadIdx.x) >> 6;
    if (dst >= n) return;
    float asv[VPL], adv[VPL];
    #pragma unroll
    for (int j = 0; j < VPL; j++) {
        asv[j] = a_s[lane * VPL + j];
        adv[j] = a_d[lane * VPL + j];
    }
    float hs[VPL];
    {
        const unsigned short* hp = h + (long)dst * F + lane * VPL;
        if (VPL == 4) {
            uint2 hv = *(const uint2*)hp;
            hs[0] = __uint_as_float(hv.x << 16); hs[1] = __uint_as_float(hv.x & 0xffff0000u);
            hs[2] = __uint_as_float(hv.y << 16); hs[3] = __uint_as_float(hv.y & 0xffff0000u);
        } else {
            unsigned int hv = *(const unsigned int*)hp;
            hs[0] = __uint_as_float(hv << 16); hs[1] = __uint_as_float(hv & 0xffff0000u);
        }
    }
    float ps = 0.f, pd = 0.f;
    #pragma unroll
    for (int j = 0; j < VPL; j++) { ps += hs[j] * asv[j]; pd += hs[j] * adv[j]; }
    #pragma unroll
    for (int m = 1; m < LPH; m <<= 1) {
        ps += __shfl_xor(ps, m, 64);
        pd += __shfl_xor(pd, m, 64);
    }
    float ed_dst = pd;
    float e = ps + ed_dst;
    e = fmaxf(e, NEG_SLOPE * e);
    float w = __expf(e);
    float z = w;
    float acc[VPL];
    #pragma unroll
    for (int j = 0; j < VPL; j++) acc[j] = w * hs[j];

    int deg = min(cnt[dst], CAP);
    const int* ap = adj + (long)dst * CAP;
    int sl = 0;
    if (deg > 0) sl = ap[lane < deg ? lane : deg - 1];
    for (int base = 0; base < deg; base += 8) {
        float hv[8][VPL];
        #pragma unroll
        for (int c = 0; c < 8; c++) {
            int idx = base + c;
            int ii = idx < deg ? idx : deg - 1;   // wave-uniform pad
            int s = __builtin_amdgcn_readlane(sl, ii);
            const unsigned short* hp = h + (long)s * F + lane * VPL;
            if (VPL == 4) {
                uint2 hb = *(const uint2*)hp;
                hv[c][0] = __uint_as_float(hb.x << 16);
                hv[c][1] = __uint_as_float(hb.x & 0xffff0000u);
                hv[c][2] = __uint_as_float(hb.y << 16);
                hv[c][3] = __uint_as_float(hb.y & 0xffff0000u);
            } else {
                unsigned int hb = *(const unsigned int*)hp;
                hv[c][0] = __uint_as_float(hb << 16);
                hv[c][1] = __uint_as_float(hb & 0xffff0000u);
            }
        }
        #pragma unroll
        for (int c = 0; c < 8; c++) {
            float p = 0.f;
            #pragma unroll
            for (int j = 0; j < VPL; j++) p += hv[c][j] * asv[j];
            #pragma unroll
            for (int m = 1; m < LPH; m <<= 1) p += __shfl_xor(p, m, 64);
            float ee = p + ed_dst;
            ee = fmaxf(ee, NEG_SLOPE * ee);
            float ww = __expf(ee);
            if (base + c >= deg) ww = 0.f;        // pad contributes nothing
            z += ww;
            #pragma unroll
            for (int j = 0; j < VPL; j++) acc[j] += ww * hv[c][j];
        }
    }
    float invz = 1.f / z;
    unsigned short pk[VPL];
    #pragma unroll
    for (int j = 0; j < VPL; j++)
        pk[j] = f2b_rne(acc[j] * invz + bias[lane * VPL + j]);
    if (VPL == 4) *(ushort4*)(out + (long)dst * F + lane * 4) = *(ushort4*)pk;
    else          *(ushort2*)(out + (long)dst * F + lane * 2) = *(ushort2*)pk;
}

// ---------------- BN stats phase A: per-block partials, NO atomics, NO fences -------
// Thread owns 8 fixed features, uint4 loads (16B/lane, coalesced). One LDS pass
// (stride-17 padding) reduces row-phases; block stores partial[b][0..F)=sum,
// partial[b][F..2F)=sumsq with plain coalesced stores. Launch-boundary = ordering.
template <int F>
__global__ __launch_bounds__(256) void k_bnpart(const unsigned short* __restrict__ x,
                                                float* __restrict__ partial, int n) {
    const int TPR = F / 8;        // threads per row
    const int RPI = 256 / TPR;    // rows per iteration
    __shared__ float sm[256 * 17];
    int t = threadIdx.x;
    int fr = t % TPR;
    int rp = t / TPR;
    int f0 = fr * 8;
    float s[8] = {}, q[8] = {};
    for (int r = blockIdx.x * RPI + rp; r < n; r += gridDim.x * RPI) {
        uint4 v = *(const uint4*)(x + (long)r * F + f0);
        const unsigned short* ev = (const unsigned short*)&v;
        #pragma unroll
        for (int j = 0; j < 8; j++) {
            float f = u2f(ev[j]);
            s[j] += f; q[j] += f * f;
        }
    }
    #pragma unroll
    for (int j = 0; j < 8; j++) { sm[t * 17 + j] = s[j]; sm[t * 17 + 8 + j] = q[j]; }
    __syncthreads();
    if (rp == 0) {
        float a[8], b[8];
        #pragma unroll
        for (int j = 0; j < 8; j++) { a[j] = sm[fr * 17 + j]; b[j] = sm[fr * 17 + 8 + j]; }
        for (int p = 1; p < RPI; p++) {
            int o = (p * TPR + fr) * 17;
            #pragma unroll
            for (int j = 0; j < 8; j++) { a[j] += sm[o + j]; b[j] += sm[o + 8 + j]; }
        }
        float* dp = partial + (long)blockIdx.x * 2 * F;
        #pragma unroll
        for (int j = 0; j < 8; j++) { dp[f0 + j] = a[j]; dp[F + f0 + j] = b[j]; }
    }
}

// ---------------- BN stats phase B: reduce partials -> scale/shift (1 block) --------
__global__ void k_bnfold(const float* __restrict__ partial,
                         const float* __restrict__ gamma, const float* __restrict__ beta,
                         float* __restrict__ scale, float* __restrict__ shift,
                         float invN, int F, int nb) {
    int t = threadIdx.x;
    if (t >= F) return;
    float s = 0.f, q = 0.f;
    for (int b = 0; b < nb; b++) {
        s += partial[(long)b * 2 * F + t];
        q += partial[(long)b * 2 * F + F + t];
    }
    float mu = s * invN;
    float var = q * invN - mu * mu;
    float sc = gamma[t] * rsqrtf(var + EPSBN);
    scale[t] = sc;
    shift[t] = beta[t] - mu * sc;
}

// ---------------- graph mean-pool (vectorized) with fused layer-2 BN+ReLU -----------
static __device__ __forceinline__ int lower_bound_i(const int* __restrict__ a, int n, int v) {
    int lo = 0, hi = n;
    while (lo < hi) { int mid = (lo + hi) >> 1; if (a[mid] < v) lo = mid + 1; else hi = mid; }
    return lo;
}

__global__ __launch_bounds__(256) void k_pool2(const unsigned short* __restrict__ x,
                                               const int* __restrict__ batch,
                                               const float* __restrict__ scale,
                                               const float* __restrict__ shift,
                                               float* __restrict__ featsum,
                                               int* __restrict__ gcnt, int n) {
    const int TPR = 32;           // threads per row (128 feats / 4 per thread)
    const int RPI = 8;            // rows per iteration
    __shared__ float sm[256 * 5];
    int g = blockIdx.x / POOL_SPLIT;
    int part = blockIdx.x % POOL_SPLIT;
    int t = threadIdx.x;
    int fr = t % TPR;
    int rp = t / TPR;
    int f0 = fr * 4;
    int lo = lower_bound_i(batch, n, g);
    int hi = lower_bound_i(batch, n, g + 1);
    float4 sc = *(const float4*)(scale + f0);
    float4 sh = *(const float4*)(shift + f0);
    float a0 = 0.f, a1 = 0.f, a2 = 0.f, a3 = 0.f;
    for (int r = lo + part * RPI + rp; r < hi; r += POOL_SPLIT * RPI) {
        uint2 v = *(const uint2*)(x + (long)r * 128 + f0);
        a0 += fmaxf(u2f((unsigned short)(v.x & 0xffff)) * sc.x + sh.x, 0.f);
        a1 += fmaxf(u2f((unsigned short)(v.x >> 16))    * sc.y + sh.y, 0.f);
        a2 += fmaxf(u2f((unsigned short)(v.y & 0xffff)) * sc.z + sh.z, 0.f);
        a3 += fmaxf(u2f((unsigned short)(v.y >> 16))    * sc.w + sh.w, 0.f);
    }
    sm[t * 5 + 0] = a0; sm[t * 5 + 1] = a1; sm[t * 5 + 2] = a2; sm[t * 5 + 3] = a3;
    __syncthreads();
    if (rp == 0) {
        float b[4];
        #pragma unroll
        for (int j = 0; j < 4; j++) b[j] = sm[fr * 5 + j];
        for (int p = 1; p < RPI; p++)
            #pragma unroll
            for (int j = 0; j < 4; j++) b[j] += sm[(p * TPR + fr) * 5 + j];
        #pragma unroll
        for (int j = 0; j < 4; j++) atomicAdd(&featsum[g * 128 + f0 + j], b[j]);
    }
    if (t == 0 && part == 0) gcnt[g] = hi - lo;
}

// ---------------- heads ----------------
__global__ void k_head(const float* __restrict__ featsum, const int* __restrict__ gcnt,
                       const float* __restrict__ clfW, const float* __restrict__ clfb,
                       const float* __restrict__ dW1, const float* __restrict__ db1,
                       const float* __restrict__ dW2, const float* __restrict__ db2,
                       void* __restrict__ out, const int* flagcnt, int G) {
    __shared__ float feat[128];
    __shared__ float dh[64];
    bool f32o = is_f32(flagcnt);
    float* of = (float*)out;
    __hip_bfloat16* ob = (__hip_bfloat16*)out;
    int g = blockIdx.x, t = threadIdx.x;  // 128 threads
    float c = fmaxf((float)gcnt[g], 1.f);
    float fv = featsum[g * 128 + t] / c;
    feat[t] = fv;
    int fidx = G * 10 + G * 2 + g * 128 + t;
    if (f32o) of[fidx] = fv; else ob[fidx] = __float2bfloat16(fv);
    __syncthreads();
    if (t < 10) {
        float a = clfb[t];
        for (int k = 0; k < 128; k++) a += feat[k] * clfW[k * 10 + t];
        int idx = g * 10 + t;
        if (f32o) of[idx] = a; else ob[idx] = __float2bfloat16(a);
    }
    if (t < 64) {
        float a = db1[t];
        for (int k = 0; k < 128; k++) a += feat[k] * dW1[k * 64 + t];
        dh[t] = a > 0.f ? a : 0.f;
    }
    __syncthreads();
    if (t < 2) {
        float a = db2[t];
        for (int k = 0; k < 64; k++) a += dh[k] * dW2[k * 2 + t];
        int idx = G * 10 + g * 2 + t;
        if (f32o) of[idx] = a; else ob[idx] = __float2bfloat16(a);
    }
}

// ---------------- launch ----------------
extern "C" void kernel_launch(void* const* d_in, const int* in_sizes, int n_in,
                              void* d_out, int out_size, void* d_ws, size_t ws_size,
                              hipStream_t stream) {
    const void* x_in = d_in[0];
    const int* ei    = (const int*)d_in[1];
    const int* batch = (const int*)d_in[2];
    const int N = in_sizes[2];
    const int E = in_sizes[1] / 2;
    const int G = 64;

    char* ws = (char*)d_ws;
    size_t off = 0;
    auto alloc = [&](size_t bytes) {
        void* p = ws + off;
        off += (bytes + 255) & ~(size_t)255;
        return p;
    };

    // ---- contiguous zero region (single memset) ----
    size_t zstart = off;
    int*   flagcnt   = (int*)alloc(256);
    float* featsum   = (float*)alloc((size_t)G * 128 * 4 + (size_t)G * 4);
    int*   gcnt      = (int*)(featsum + G * 128);
    int*   cnt       = (int*)alloc((size_t)N * 4);
    size_t zbytes = off - zstart;

    int*   adj     = (int*)alloc((size_t)N * CAP * 4);
    unsigned short* xbuf16 = (unsigned short*)alloc((size_t)N * 256 * 2);  // agg out bf16
    unsigned short* hbuf   = (unsigned short*)alloc((size_t)N * 256 * 2);  // gemm out bf16
    unsigned short* xb16   = (unsigned short*)alloc((size_t)N * 256 * 2);  // x bf16 (L0 A)
    unsigned short* Wt0    = (unsigned short*)alloc((size_t)256 * 128 * 2);
    unsigned short* Wt1    = (unsigned short*)alloc((size_t)256 * 256 * 2);
    unsigned short* Wt2    = (unsigned short*)alloc((size_t)128 * 256 * 2);
    float* bnpart  = (float*)alloc((size_t)BNB * 512 * 4);    // per-block partials (reused)
    float* bnscale = (float*)alloc(3 * 512 * 4);              // [layer][scale|shift]

    float* sc0 = bnscale,        *sh0 = bnscale + 256;
    float* sc1 = bnscale + 512,  *sh1 = bnscale + 768;
    float* sc2 = bnscale + 1024, *sh2 = bnscale + 1280;

    // fp32 copies of the 24 float param tensors (d_in[3..26])
    CvtTab tab;
    float* pp[NPARAM];
    int ptot = 0;
    for (int j = 0; j < NPARAM; j++) {
        int cnt_j = in_sizes[3 + j];
        pp[j] = (float*)alloc((size_t)cnt_j * 4);
        tab.src[j] = d_in[3 + j];
        tab.dst[j] = pp[j];
        tab.off[j] = ptot;
        ptot += cnt_j;
    }
    tab.off[NPARAM] = ptot;
    float *asf0 = pp[1], *adf0 = pp[2], *bf0 = pp[3], *gf0 = pp[4], *bef0 = pp[5];
    float *asf1 = pp[7], *adf1 = pp[8], *bf1 = pp[9], *gf1 = pp[10], *bef1 = pp[11];
    float *asf2 = pp[13], *adf2 = pp[14], *bf2 = pp[15], *gf2 = pp[16], *bef2 = pp[17];
    float *clfWf = pp[18], *clfbf = pp[19], *dW1f = pp[20], *db1f = pp[21], *dW2f = pp[22], *db2f = pp[23];

    const int TPB = 256;
    int wgrid = (N + 3) / 4;
    int mblocks = (N + 63) / 64;
    float invN = 1.f / (float)N;

    hipMemsetAsync(ws + zstart, 0, zbytes, stream);
    k_detect<<<1, 256, 0, stream>>>((const unsigned short*)x_in, flagcnt);
    k_prep<<<2048, TPB, 0, stream>>>(x_in, xb16, tab, Wt0, Wt1, Wt2, flagcnt, N * 128, ptot);
    k_fill_graph<<<(E + TPB - 1) / TPB, TPB, 0, stream>>>(ei, cnt, adj, E);

    // ---- layer 0: K=128 -> F=256, H=4 (no input BN) ----
    k_gemm_mfma<<<dim3(mblocks, 4), 256, 0, stream>>>(xb16, Wt0, hbuf, nullptr, nullptr, N, 128, 256);
    k_agg<256, 4><<<wgrid, 256, 0, stream>>>(hbuf, cnt, adj, asf0, adf0, bf0, xbuf16, N);
    k_bnpart<256><<<BNB, 256, 0, stream>>>(xbuf16, bnpart, N);
    k_bnfold<<<1, 256, 0, stream>>>(bnpart, gf0, bef0, sc0, sh0, invN, 256, BNB);

    // ---- layer 1: K=256 -> F=256, H=4 (BN0 fused into A-staging) ----
    k_gemm_mfma<<<dim3(mblocks, 4), 256, 0, stream>>>(xbuf16, Wt1, hbuf, sc0, sh0, N, 256, 256);
    k_agg<256, 4><<<wgrid, 256, 0, stream>>>(hbuf, cnt, adj, asf1, adf1, bf1, xbuf16, N);
    k_bnpart<256><<<BNB, 256, 0, stream>>>(xbuf16, bnpart, N);
    k_bnfold<<<1, 256, 0, stream>>>(bnpart, gf1, bef1, sc1, sh1, invN, 256, BNB);

    // ---- layer 2: K=256 -> F=128, H=1 (BN1 fused into A-staging) ----
    k_gemm_mfma<<<dim3(mblocks, 2), 256, 0, stream>>>(xbuf16, Wt2, hbuf, sc1, sh1, N, 256, 128);
    k_agg<128, 1><<<wgrid, 256, 0, stream>>>(hbuf, cnt, adj, asf2, adf2, bf2, xbuf16, N);
    k_bnpart<128><<<BNB, 256, 0, stream>>>(xbuf16, bnpart, N);
    k_bnfold<<<1, 128, 0, stream>>>(bnpart, gf2, bef2, sc2, sh2, invN, 128, BNB);

    // ---- pooling (BN2 fused) + heads ----
    k_pool2<<<G * POOL_SPLIT, 256, 0, stream>>>(xbuf16, batch, sc2, sh2, featsum, gcnt, N);
    k_head<<<G, 128, 0, stream>>>(featsum, gcnt, clfWf, clfbf, dW1f, db1f, dW2f, db2f,
                                  d_out, flagcnt, G);
}

// Round 12
// 316.029 us; speedup vs baseline: 1.5927x; 1.5924x over previous
//
#include <hip/hip_runtime.h>
#include <hip/hip_bf16.h>

#define CAP 64          // max real in-neighbors kept per dst (self-loop is implicit)
#define EPSBN 1e-5f
#define NEG_SLOPE 0.2f
#define NPARAM 24       // float param tensors: d_in[3..26]
#define POOL_SPLIT 4    // blocks per graph in pooling
#define BNB 256         // blocks for bn partial pass

typedef __attribute__((ext_vector_type(8))) short short8;
typedef __attribute__((ext_vector_type(4))) float f32x4;

static __device__ __forceinline__ float b2f(__hip_bfloat16 v) { return __bfloat162float(v); }
static __device__ __forceinline__ float u2f(unsigned short u) {  // bf16 bits -> float
    return __uint_as_float(((unsigned int)u) << 16);
}
static __device__ __forceinline__ unsigned short f2b_rne(float f) {  // float -> bf16, RNE
    unsigned int u = __float_as_uint(f);
    u += 0x7FFF + ((u >> 16) & 1);
    return (unsigned short)(u >> 16);
}
static __device__ __forceinline__ bool is_f32(const int* flagcnt) { return *flagcnt > 32; }

// ---------------- dtype probe ----------------
__global__ void k_detect(const unsigned short* __restrict__ raw, int* flagcnt) {
    int t = threadIdx.x;  // 256 threads, 1 block
    int c = 0;
    for (int i = t; i < 4096; i += 256) {
        int e = (raw[i] >> 7) & 0xFF;
        if (e >= 200) c++;
    }
    atomicAdd(flagcnt, c);
}

// ---------------- merged prep: x->bf16, params->fp32, W0/1/2 -> transposed bf16 ------
struct CvtTab {
    const void* src[NPARAM];
    float* dst[NPARAM];
    int off[NPARAM + 1];
};

__global__ void k_prep(const void* __restrict__ x_in, unsigned short* __restrict__ xb16,
                       CvtTab tab,
                       unsigned short* __restrict__ Wt0, unsigned short* __restrict__ Wt1,
                       unsigned short* __restrict__ Wt2,
                       const int* flagcnt, int NX, int ptot) {
    bool f32 = is_f32(flagcnt);
    const void* W0r = tab.src[0];
    const void* W1r = tab.src[6];
    const void* W2r = tab.src[12];
    int b0 = NX, b1 = b0 + ptot, b2 = b1 + 256 * 128, b3 = b2 + 256 * 256, b4 = b3 + 128 * 256;
    for (int i = blockIdx.x * blockDim.x + threadIdx.x; i < b4; i += gridDim.x * blockDim.x) {
        if (i < b0) {
            xb16[i] = f32 ? f2b_rne(((const float*)x_in)[i]) : ((const unsigned short*)x_in)[i];
        } else if (i < b1) {
            int ii = i - b0;
            int j = 0;
            while (tab.off[j + 1] <= ii) j++;
            int k = ii - tab.off[j];
            tab.dst[j][k] = f32 ? ((const float*)tab.src[j])[k]
                                : b2f(((const __hip_bfloat16*)tab.src[j])[k]);
        } else if (i < b2) {         // Wt0 [F=256][K=128] <- W0 [128,256]
            int ii = i - b1;
            int f = ii >> 7, k = ii & 127;
            long src = (long)k * 256 + f;
            Wt0[ii] = f32 ? f2b_rne(((const float*)W0r)[src]) : ((const unsigned short*)W0r)[src];
        } else if (i < b3) {         // Wt1 [256][256] <- W1 [256,256]
            int ii = i - b2;
            int f = ii >> 8, k = ii & 255;
            long src = (long)k * 256 + f;
            Wt1[ii] = f32 ? f2b_rne(((const float*)W1r)[src]) : ((const unsigned short*)W1r)[src];
        } else {                     // Wt2 [F=128][K=256] <- W2 [256,128]
            int ii = i - b3;
            int f = ii >> 8, k = ii & 255;
            long src = (long)k * 128 + f;
            Wt2[ii] = f32 ? f2b_rne(((const float*)W2r)[src]) : ((const unsigned short*)W2r)[src];
        }
    }
}

// ---------------- graph build (cnt pre-zeroed by memset; self-loop implicit) ---------
__global__ void k_fill_graph(const int* __restrict__ ei, int* cnt, int* adj, int E) {
    int e = blockIdx.x * blockDim.x + threadIdx.x;
    if (e < E) {
        int s = ei[e];
        int d = ei[E + e];
        int slot = atomicAdd(&cnt[d], 1);
        if (slot < CAP) adj[d * CAP + slot] = s;
    }
}

// ---------------- bf16 MFMA GEMM, optional fused BN+ReLU on the A operand -----------
// C[M,F] = bn(A)[M,K] @ Bt[F,K]^T.  bn(x) = relu(x*scale[k]+shift[k]) if scale!=null.
__global__ __launch_bounds__(256) void k_gemm_mfma(const unsigned short* __restrict__ A,
                                                   const unsigned short* __restrict__ Bt,
                                                   unsigned short* __restrict__ C,
                                                   const float* __restrict__ scale,
                                                   const float* __restrict__ shift,
                                                   int M, int K, int F) {
    __shared__ __align__(16) unsigned short As[64 * 40];
    __shared__ __align__(16) unsigned short Bs[64 * 40];
    int t = threadIdx.x;
    int lane = t & 63, wave = t >> 6;
    int wm = wave & 1, wf = wave >> 1;
    int m0 = blockIdx.x * 64, f0 = blockIdx.y * 64;
    int r = lane & 15, q = lane >> 4;
    int srow = t >> 2, schunk = t & 3;
    f32x4 acc[2][2] = {};
    for (int k0 = 0; k0 < K; k0 += 32) {
        uint4 av = {0, 0, 0, 0};
        int gr = m0 + srow;
        if (gr < M) {
            av = *(const uint4*)(A + (long)gr * K + k0 + schunk * 8);
            if (scale) {
                int fb = k0 + schunk * 8;
                float4 s0 = *(const float4*)(scale + fb);
                float4 s1 = *(const float4*)(scale + fb + 4);
                float4 h0 = *(const float4*)(shift + fb);
                float4 h1 = *(const float4*)(shift + fb + 4);
                unsigned short* ev = (unsigned short*)&av;
                ev[0] = f2b_rne(fmaxf(u2f(ev[0]) * s0.x + h0.x, 0.f));
                ev[1] = f2b_rne(fmaxf(u2f(ev[1]) * s0.y + h0.y, 0.f));
                ev[2] = f2b_rne(fmaxf(u2f(ev[2]) * s0.z + h0.z, 0.f));
                ev[3] = f2b_rne(fmaxf(u2f(ev[3]) * s0.w + h0.w, 0.f));
                ev[4] = f2b_rne(fmaxf(u2f(ev[4]) * s1.x + h1.x, 0.f));
                ev[5] = f2b_rne(fmaxf(u2f(ev[5]) * s1.y + h1.y, 0.f));
                ev[6] = f2b_rne(fmaxf(u2f(ev[6]) * s1.z + h1.z, 0.f));
                ev[7] = f2b_rne(fmaxf(u2f(ev[7]) * s1.w + h1.w, 0.f));
            }
        }
        *(uint4*)&As[srow * 40 + schunk * 8] = av;
        uint4 bv = *(const uint4*)(Bt + (long)(f0 + srow) * K + k0 + schunk * 8);
        *(uint4*)&Bs[srow * 40 + schunk * 8] = bv;
        __syncthreads();
        short8 a0 = *(short8*)&As[(wm * 32 + r) * 40 + q * 8];
        short8 a1 = *(short8*)&As[(wm * 32 + 16 + r) * 40 + q * 8];
        short8 b0 = *(short8*)&Bs[(wf * 32 + r) * 40 + q * 8];
        short8 b1 = *(short8*)&Bs[(wf * 32 + 16 + r) * 40 + q * 8];
        acc[0][0] = __builtin_amdgcn_mfma_f32_16x16x32_bf16(a0, b0, acc[0][0], 0, 0, 0);
        acc[0][1] = __builtin_amdgcn_mfma_f32_16x16x32_bf16(a0, b1, acc[0][1], 0, 0, 0);
        acc[1][0] = __builtin_amdgcn_mfma_f32_16x16x32_bf16(a1, b0, acc[1][0], 0, 0, 0);
        acc[1][1] = __builtin_amdgcn_mfma_f32_16x16x32_bf16(a1, b1, acc[1][1], 0, 0, 0);
        __syncthreads();
    }
    #pragma unroll
    for (int mt = 0; mt < 2; mt++) {
        #pragma unroll
        for (int reg = 0; reg < 4; reg++) {
            int row = m0 + wm * 32 + mt * 16 + q * 4 + reg;
            if (row < M) {
                C[(long)row * F + f0 + wf * 32 + r]      = f2b_rne(acc[mt][0][reg]);
                C[(long)row * F + f0 + wf * 32 + 16 + r] = f2b_rne(acc[mt][1][reg]);
            }
        }
    }
}

// ---------------- fused attention: coefficients + softmax + aggregation --------------
template <int F, int H>
__global__ __launch_bounds__(256) void k_agg(const unsigned short* __restrict__ h,
                      const int* __restrict__ cnt, const int* __restrict__ adj,
                      const float* __restrict__ a_s, const float* __restrict__ a_d,
                      const float* __restrict__ bias,
                      unsigned short* __restrict__ out, int n) {
    const int VPL = F / 64;
    const int LPH = 64 / H;   // lanes per head
    int lane = threadIdx.x & 63;
    int dst = (blockIdx.x * blockDim.x + threadIdx.x) >> 6;
    if (dst >= n) return;
    float asv[VPL], adv[VPL];
    #pragma unroll
    for (int j = 0; j < VPL; j++) {
        asv[j] = a_s[lane * VPL + j];
        adv[j] = a_d[lane * VPL + j];
    }
    float hs[VPL];
    {
        const unsigned short* hp = h + (long)dst * F + lane * VPL;
        if (VPL == 4) {
            uint2 hv = *(const uint2*)hp;
            hs[0] = __uint_as_float(hv.x << 16); hs[1] = __uint_as_float(hv.x & 0xffff0000u);
            hs[2] = __uint_as_float(hv.y << 16); hs[3] = __uint_as_float(hv.y & 0xffff0000u);
        } else {
            unsigned int hv = *(const unsigned int*)hp;
            hs[0] = __uint_as_float(hv << 16); hs[1] = __uint_as_float(hv & 0xffff0000u);
        }
    }
    float ps = 0.f, pd = 0.f;
    #pragma unroll
    for (int j = 0; j < VPL; j++) { ps += hs[j] * asv[j]; pd += hs[j] * adv[j]; }
    #pragma unroll
    for (int m = 1; m < LPH; m <<= 1) {
        ps += __shfl_xor(ps, m, 64);
        pd += __shfl_xor(pd, m, 64);
    }
    float ed_dst = pd;
    float e = ps + ed_dst;
    e = fmaxf(e, NEG_SLOPE * e);
    float w = __expf(e);
    float z = w;
    float acc[VPL];
    #pragma unroll
    for (int j = 0; j < VPL; j++) acc[j] = w * hs[j];

    int deg = min(cnt[dst], CAP);
    const int* ap = adj + (long)dst * CAP;
    int sl = 0;
    if (deg > 0) sl = ap[lane < deg ? lane : deg - 1];
    for (int base = 0; base < deg; base += 8) {
        float hv[8][VPL];
        #pragma unroll
        for (int c = 0; c < 8; c++) {
            int idx = base + c;
            int ii = idx < deg ? idx : deg - 1;   // wave-uniform pad
            int s = __builtin_amdgcn_readlane(sl, ii);
            const unsigned short* hp = h + (long)s * F + lane * VPL;
            if (VPL == 4) {
                uint2 hb = *(const uint2*)hp;
                hv[c][0] = __uint_as_float(hb.x << 16);
                hv[c][1] = __uint_as_float(hb.x & 0xffff0000u);
                hv[c][2] = __uint_as_float(hb.y << 16);
                hv[c][3] = __uint_as_float(hb.y & 0xffff0000u);
            } else {
                unsigned int hb = *(const unsigned int*)hp;
                hv[c][0] = __uint_as_float(hb << 16);
                hv[c][1] = __uint_as_float(hb & 0xffff0000u);
            }
        }
        #pragma unroll
        for (int c = 0; c < 8; c++) {
            float p = 0.f;
            #pragma unroll
            for (int j = 0; j < VPL; j++) p += hv[c][j] * asv[j];
            #pragma unroll
            for (int m = 1; m < LPH; m <<= 1) p += __shfl_xor(p, m, 64);
            float ee = p + ed_dst;
            ee = fmaxf(ee, NEG_SLOPE * ee);
            float ww = __expf(ee);
            if (base + c >= deg) ww = 0.f;        // pad contributes nothing
            z += ww;
            #pragma unroll
            for (int j = 0; j < VPL; j++) acc[j] += ww * hv[c][j];
        }
    }
    float invz = 1.f / z;
    unsigned short pk[VPL];
    #pragma unroll
    for (int j = 0; j < VPL; j++)
        pk[j] = f2b_rne(acc[j] * invz + bias[lane * VPL + j]);
    if (VPL == 4) *(ushort4*)(out + (long)dst * F + lane * 4) = *(ushort4*)pk;
    else          *(ushort2*)(out + (long)dst * F + lane * 2) = *(ushort2*)pk;
}

// ---------------- BN stats phase A: per-block partials, NO atomics, NO fences -------
template <int F>
__global__ __launch_bounds__(256) void k_bnpart(const unsigned short* __restrict__ x,
                                                float* __restrict__ partial, int n) {
    const int TPR = F / 8;        // threads per row
    const int RPI = 256 / TPR;    // rows per iteration
    __shared__ float sm[256 * 17];
    int t = threadIdx.x;
    int fr = t % TPR;
    int rp = t / TPR;
    int f0 = fr * 8;
    float s[8] = {}, q[8] = {};
    for (int r = blockIdx.x * RPI + rp; r < n; r += gridDim.x * RPI) {
        uint4 v = *(const uint4*)(x + (long)r * F + f0);
        const unsigned short* ev = (const unsigned short*)&v;
        #pragma unroll
        for (int j = 0; j < 8; j++) {
            float f = u2f(ev[j]);
            s[j] += f; q[j] += f * f;
        }
    }
    #pragma unroll
    for (int j = 0; j < 8; j++) { sm[t * 17 + j] = s[j]; sm[t * 17 + 8 + j] = q[j]; }
    __syncthreads();
    if (rp == 0) {
        float a[8], b[8];
        #pragma unroll
        for (int j = 0; j < 8; j++) { a[j] = sm[fr * 17 + j]; b[j] = sm[fr * 17 + 8 + j]; }
        for (int p = 1; p < RPI; p++) {
            int o = (p * TPR + fr) * 17;
            #pragma unroll
            for (int j = 0; j < 8; j++) { a[j] += sm[o + j]; b[j] += sm[o + 8 + j]; }
        }
        float* dp = partial + (long)blockIdx.x * 2 * F;
        #pragma unroll
        for (int j = 0; j < 8; j++) { dp[f0 + j] = a[j]; dp[F + f0 + j] = b[j]; }
    }
}

// ---------------- BN stats phase B: parallel fold, one wave per feature -------------
// grid = F blocks x 64 lanes; lane l sums partials b = l, l+64, ... (8 independent
// loads in flight), 64-lane butterfly reduce, lane 0 writes scale/shift.
__global__ __launch_bounds__(64) void k_bnfold(const float* __restrict__ partial,
                         const float* __restrict__ gamma, const float* __restrict__ beta,
                         float* __restrict__ scale, float* __restrict__ shift,
                         float invN, int F, int nb) {
    int f = blockIdx.x;
    int l = threadIdx.x;
    float s = 0.f, q = 0.f;
    for (int b = l; b < nb; b += 64) {
        s += partial[(long)b * 2 * F + f];
        q += partial[(long)b * 2 * F + F + f];
    }
    #pragma unroll
    for (int m = 1; m < 64; m <<= 1) {
        s += __shfl_xor(s, m, 64);
        q += __shfl_xor(q, m, 64);
    }
    if (l == 0) {
        float mu = s * invN;
        float var = q * invN - mu * mu;
        float sc = gamma[f] * rsqrtf(var + EPSBN);
        scale[f] = sc;
        shift[f] = beta[f] - mu * sc;
    }
}

// ---------------- graph mean-pool (vectorized) with fused layer-2 BN+ReLU -----------
static __device__ __forceinline__ int lower_bound_i(const int* __restrict__ a, int n, int v) {
    int lo = 0, hi = n;
    while (lo < hi) { int mid = (lo + hi) >> 1; if (a[mid] < v) lo = mid + 1; else hi = mid; }
    return lo;
}

__global__ __launch_bounds__(256) void k_pool2(const unsigned short* __restrict__ x,
                                               const int* __restrict__ batch,
                                               const float* __restrict__ scale,
                                               const float* __restrict__ shift,
                                               float* __restrict__ featsum,
                                               int* __restrict__ gcnt, int n) {
    const int TPR = 32;           // threads per row (128 feats / 4 per thread)
    const int RPI = 8;            // rows per iteration
    __shared__ float sm[256 * 5];
    int g = blockIdx.x / POOL_SPLIT;
    int part = blockIdx.x % POOL_SPLIT;
    int t = threadIdx.x;
    int fr = t % TPR;
    int rp = t / TPR;
    int f0 = fr * 4;
    int lo = lower_bound_i(batch, n, g);
    int hi = lower_bound_i(batch, n, g + 1);
    float4 sc = *(const float4*)(scale + f0);
    float4 sh = *(const float4*)(shift + f0);
    float a0 = 0.f, a1 = 0.f, a2 = 0.f, a3 = 0.f;
    for (int r = lo + part * RPI + rp; r < hi; r += POOL_SPLIT * RPI) {
        uint2 v = *(const uint2*)(x + (long)r * 128 + f0);
        a0 += fmaxf(u2f((unsigned short)(v.x & 0xffff)) * sc.x + sh.x, 0.f);
        a1 += fmaxf(u2f((unsigned short)(v.x >> 16))    * sc.y + sh.y, 0.f);
        a2 += fmaxf(u2f((unsigned short)(v.y & 0xffff)) * sc.z + sh.z, 0.f);
        a3 += fmaxf(u2f((unsigned short)(v.y >> 16))    * sc.w + sh.w, 0.f);
    }
    sm[t * 5 + 0] = a0; sm[t * 5 + 1] = a1; sm[t * 5 + 2] = a2; sm[t * 5 + 3] = a3;
    __syncthreads();
    if (rp == 0) {
        float b[4];
        #pragma unroll
        for (int j = 0; j < 4; j++) b[j] = sm[fr * 5 + j];
        for (int p = 1; p < RPI; p++)
            #pragma unroll
            for (int j = 0; j < 4; j++) b[j] += sm[(p * TPR + fr) * 5 + j];
        #pragma unroll
        for (int j = 0; j < 4; j++) atomicAdd(&featsum[g * 128 + f0 + j], b[j]);
    }
    if (t == 0 && part == 0) gcnt[g] = hi - lo;
}

// ---------------- heads ----------------
__global__ void k_head(const float* __restrict__ featsum, const int* __restrict__ gcnt,
                       const float* __restrict__ clfW, const float* __restrict__ clfb,
                       const float* __restrict__ dW1, const float* __restrict__ db1,
                       const float* __restrict__ dW2, const float* __restrict__ db2,
                       void* __restrict__ out, const int* flagcnt, int G) {
    __shared__ float feat[128];
    __shared__ float dh[64];
    bool f32o = is_f32(flagcnt);
    float* of = (float*)out;
    __hip_bfloat16* ob = (__hip_bfloat16*)out;
    int g = blockIdx.x, t = threadIdx.x;  // 128 threads
    float c = fmaxf((float)gcnt[g], 1.f);
    float fv = featsum[g * 128 + t] / c;
    feat[t] = fv;
    int fidx = G * 10 + G * 2 + g * 128 + t;
    if (f32o) of[fidx] = fv; else ob[fidx] = __float2bfloat16(fv);
    __syncthreads();
    if (t < 10) {
        float a = clfb[t];
        for (int k = 0; k < 128; k++) a += feat[k] * clfW[k * 10 + t];
        int idx = g * 10 + t;
        if (f32o) of[idx] = a; else ob[idx] = __float2bfloat16(a);
    }
    if (t < 64) {
        float a = db1[t];
        for (int k = 0; k < 128; k++) a += feat[k] * dW1[k * 64 + t];
        dh[t] = a > 0.f ? a : 0.f;
    }
    __syncthreads();
    if (t < 2) {
        float a = db2[t];
        for (int k = 0; k < 64; k++) a += dh[k] * dW2[k * 2 + t];
        int idx = G * 10 + g * 2 + t;
        if (f32o) of[idx] = a; else ob[idx] = __float2bfloat16(a);
    }
}

// ---------------- launch ----------------
extern "C" void kernel_launch(void* const* d_in, const int* in_sizes, int n_in,
                              void* d_out, int out_size, void* d_ws, size_t ws_size,
                              hipStream_t stream) {
    const void* x_in = d_in[0];
    const int* ei    = (const int*)d_in[1];
    const int* batch = (const int*)d_in[2];
    const int N = in_sizes[2];
    const int E = in_sizes[1] / 2;
    const int G = 64;

    char* ws = (char*)d_ws;
    size_t off = 0;
    auto alloc = [&](size_t bytes) {
        void* p = ws + off;
        off += (bytes + 255) & ~(size_t)255;
        return p;
    };

    // ---- contiguous zero region (single memset) ----
    size_t zstart = off;
    int*   flagcnt   = (int*)alloc(256);
    float* featsum   = (float*)alloc((size_t)G * 128 * 4 + (size_t)G * 4);
    int*   gcnt      = (int*)(featsum + G * 128);
    int*   cnt       = (int*)alloc((size_t)N * 4);
    size_t zbytes = off - zstart;

    int*   adj     = (int*)alloc((size_t)N * CAP * 4);
    unsigned short* xbuf16 = (unsigned short*)alloc((size_t)N * 256 * 2);  // agg out bf16
    unsigned short* hbuf   = (unsigned short*)alloc((size_t)N * 256 * 2);  // gemm out bf16
    unsigned short* xb16   = (unsigned short*)alloc((size_t)N * 256 * 2);  // x bf16 (L0 A)
    unsigned short* Wt0    = (unsigned short*)alloc((size_t)256 * 128 * 2);
    unsigned short* Wt1    = (unsigned short*)alloc((size_t)256 * 256 * 2);
    unsigned short* Wt2    = (unsigned short*)alloc((size_t)128 * 256 * 2);
    float* bnpart  = (float*)alloc((size_t)BNB * 512 * 4);    // per-block partials (reused)
    float* bnscale = (float*)alloc(3 * 512 * 4);              // [layer][scale|shift]

    float* sc0 = bnscale,        *sh0 = bnscale + 256;
    float* sc1 = bnscale + 512,  *sh1 = bnscale + 768;
    float* sc2 = bnscale + 1024, *sh2 = bnscale + 1280;

    // fp32 copies of the 24 float param tensors (d_in[3..26])
    CvtTab tab;
    float* pp[NPARAM];
    int ptot = 0;
    for (int j = 0; j < NPARAM; j++) {
        int cnt_j = in_sizes[3 + j];
        pp[j] = (float*)alloc((size_t)cnt_j * 4);
        tab.src[j] = d_in[3 + j];
        tab.dst[j] = pp[j];
        tab.off[j] = ptot;
        ptot += cnt_j;
    }
    tab.off[NPARAM] = ptot;
    float *asf0 = pp[1], *adf0 = pp[2], *bf0 = pp[3], *gf0 = pp[4], *bef0 = pp[5];
    float *asf1 = pp[7], *adf1 = pp[8], *bf1 = pp[9], *gf1 = pp[10], *bef1 = pp[11];
    float *asf2 = pp[13], *adf2 = pp[14], *bf2 = pp[15], *gf2 = pp[16], *bef2 = pp[17];
    float *clfWf = pp[18], *clfbf = pp[19], *dW1f = pp[20], *db1f = pp[21], *dW2f = pp[22], *db2f = pp[23];

    const int TPB = 256;
    int wgrid = (N + 3) / 4;
    int mblocks = (N + 63) / 64;
    float invN = 1.f / (float)N;

    hipMemsetAsync(ws + zstart, 0, zbytes, stream);
    k_detect<<<1, 256, 0, stream>>>((const unsigned short*)x_in, flagcnt);
    k_prep<<<2048, TPB, 0, stream>>>(x_in, xb16, tab, Wt0, Wt1, Wt2, flagcnt, N * 128, ptot);
    k_fill_graph<<<(E + TPB - 1) / TPB, TPB, 0, stream>>>(ei, cnt, adj, E);

    // ---- layer 0: K=128 -> F=256, H=4 (no input BN) ----
    k_gemm_mfma<<<dim3(mblocks, 4), 256, 0, stream>>>(xb16, Wt0, hbuf, nullptr, nullptr, N, 128, 256);
    k_agg<256, 4><<<wgrid, 256, 0, stream>>>(hbuf, cnt, adj, asf0, adf0, bf0, xbuf16, N);
    k_bnpart<256><<<BNB, 256, 0, stream>>>(xbuf16, bnpart, N);
    k_bnfold<<<256, 64, 0, stream>>>(bnpart, gf0, bef0, sc0, sh0, invN, 256, BNB);

    // ---- layer 1: K=256 -> F=256, H=4 (BN0 fused into A-staging) ----
    k_gemm_mfma<<<dim3(mblocks, 4), 256, 0, stream>>>(xbuf16, Wt1, hbuf, sc0, sh0, N, 256, 256);
    k_agg<256, 4><<<wgrid, 256, 0, stream>>>(hbuf, cnt, adj, asf1, adf1, bf1, xbuf16, N);
    k_bnpart<256><<<BNB, 256, 0, stream>>>(xbuf16, bnpart, N);
    k_bnfold<<<256, 64, 0, stream>>>(bnpart, gf1, bef1, sc1, sh1, invN, 256, BNB);

    // ---- layer 2: K=256 -> F=128, H=1 (BN1 fused into A-staging) ----
    k_gemm_mfma<<<dim3(mblocks, 2), 256, 0, stream>>>(xbuf16, Wt2, hbuf, sc1, sh1, N, 256, 128);
    k_agg<128, 1><<<wgrid, 256, 0, stream>>>(hbuf, cnt, adj, asf2, adf2, bf2, xbuf16, N);
    k_bnpart<128><<<BNB, 256, 0, stream>>>(xbuf16, bnpart, N);
    k_bnfold<<<128, 64, 0, stream>>>(bnpart, gf2, bef2, sc2, sh2, invN, 128, BNB);

    // ---- pooling (BN2 fused) + heads ----
    k_pool2<<<G * POOL_SPLIT, 256, 0, stream>>>(xbuf16, batch, sc2, sh2, featsum, gcnt, N);
    k_head<<<G, 128, 0, stream>>>(featsum, gcnt, clfWf, clfbf, dW1f, db1f, dW2f, db2f,
                                  d_out, flagcnt, G);
}